// Round 1
// baseline (780.566 us; speedup 1.0000x reference)
//
#include <hip/hip_runtime.h>
#include <hip/hip_bf16.h>

#define B_    16
#define CIN_  1024
#define T_    2000
#define BN_   512
#define OUT_  512
#define NBR_  3
#define TP_X  2048   // xbT padded t-extent
#define TP_H  2056   // hT padded t-extent (index = t + HOFF)
#define HOFF  4

typedef float  f32x4  __attribute__((ext_vector_type(4)));
typedef __bf16 bf16x8 __attribute__((ext_vector_type(8)));
typedef unsigned short u16;
typedef u16 u16x4 __attribute__((ext_vector_type(4)));
typedef u16 u16x8 __attribute__((ext_vector_type(8)));

static __device__ __forceinline__ float b2f(u16 u) {
    union { float f; unsigned int i; } v; v.i = ((unsigned int)u) << 16; return v.f;
}
static __device__ __forceinline__ u16 f2b(float f) {
    __hip_bfloat16 h = __float2bfloat16(f);   // RNE
    u16 r; __builtin_memcpy(&r, &h, 2); return r;
}

// ---------------------------------------------------------------------------
// K1: x[b,c,t] --BN1+ReLU--> bf16, transposed to xbT[b][t][c], t padded to 2048
// ---------------------------------------------------------------------------
__global__ __launch_bounds__(256) void k_prep_x(
    const float* __restrict__ x, const float* __restrict__ g,
    const float* __restrict__ be, const float* __restrict__ mu,
    const float* __restrict__ va, u16* __restrict__ xbT)
{
    __shared__ float tile[32][33];
    int b = blockIdx.z, c0 = blockIdx.y * 32, t0 = blockIdx.x * 32;
    int tid = threadIdx.x;
    // load phase: 32 c-rows x 32 t (as 8 float4 per row)
    int cl = tid >> 3, tt = (tid & 7) * 4;
    int c = c0 + cl;
    float inv = g[c] / sqrtf(va[c] + 1e-5f);
    float bia = be[c] - mu[c] * inv;
    int t = t0 + tt;
    float y0 = 0.f, y1 = 0.f, y2 = 0.f, y3 = 0.f;
    if (t < T_) {   // t multiple of 4, so t<T_ implies t+3<T_
        float4 v = *reinterpret_cast<const float4*>(x + (size_t)(b * CIN_ + c) * T_ + t);
        y0 = fmaxf(v.x * inv + bia, 0.f);
        y1 = fmaxf(v.y * inv + bia, 0.f);
        y2 = fmaxf(v.z * inv + bia, 0.f);
        y3 = fmaxf(v.w * inv + bia, 0.f);
    }
    tile[tt + 0][cl] = y0; tile[tt + 1][cl] = y1;
    tile[tt + 2][cl] = y2; tile[tt + 3][cl] = y3;
    __syncthreads();
    // store phase: 32 t-rows x 32 c (as 8 u16x4 per row)
    int tl = tid >> 3, c8 = (tid & 7) * 4;
    u16x4 o;
    o.x = f2b(tile[tl][c8 + 0]);
    o.y = f2b(tile[tl][c8 + 1]);
    o.z = f2b(tile[tl][c8 + 2]);
    o.w = f2b(tile[tl][c8 + 3]);
    *reinterpret_cast<u16x4*>(xbT + (size_t)(b * TP_X + t0 + tl) * CIN_ + c0 + c8) = o;
}

// ---------------------------------------------------------------------------
// K2: W1b[o][c] = bf16(W1[o][c] * inv2[o]);  bias2[o] = beta2 - mean2*inv2
// ---------------------------------------------------------------------------
__global__ __launch_bounds__(256) void k_prep_w1(
    const float* __restrict__ W1, const float* __restrict__ g,
    const float* __restrict__ be, const float* __restrict__ mu,
    const float* __restrict__ va, u16* __restrict__ W1b, float* __restrict__ bias2)
{
    int i = blockIdx.x * 256 + threadIdx.x;   // 512*256 threads, 4 elems each
    int o = i >> 8;
    int c = (i & 255) * 4;
    float inv = g[o] / sqrtf(va[o] + 1e-5f);
    if (c == 0) bias2[o] = be[o] - mu[o] * inv;
    float4 w = *reinterpret_cast<const float4*>(W1 + (size_t)o * CIN_ + c);
    u16x4 r;
    r.x = f2b(w.x * inv); r.y = f2b(w.y * inv);
    r.z = f2b(w.z * inv); r.w = f2b(w.w * inv);
    *reinterpret_cast<u16x4*>(W1b + (size_t)o * CIN_ + c) = r;
}

// ---------------------------------------------------------------------------
// K3: conv_w[n][o][c][k] -> wb[n][k][o][c] bf16
// ---------------------------------------------------------------------------
__global__ __launch_bounds__(256) void k_prep_wc(
    const float* __restrict__ cw, u16* __restrict__ wb)
{
    int i = blockIdx.x * 256 + threadIdx.x;   // over 3*512*512 = (n*512+o)*512+c
    if (i >= NBR_ * OUT_ * BN_) return;
    int c = i & 511;
    int o = (i >> 9) & 511;
    int n = i >> 18;
    const float* p = cw + (size_t)i * 3;
#pragma unroll
    for (int k = 0; k < 3; k++)
        wb[((size_t)(n * 3 + k) * OUT_ + o) * BN_ + c] = f2b(p[k]);
}

// ---------------------------------------------------------------------------
// K4: zero hT pad rows (idx [0,4) and [2004,2056)) — ws is re-poisoned each call
// ---------------------------------------------------------------------------
__global__ __launch_bounds__(256) void k_zero_hpad(u16* __restrict__ hT)
{
    int i = blockIdx.x * 256 + threadIdx.x;   // 16*56*512
    if (i >= B_ * 56 * BN_) return;
    int c = i & 511;
    int p = (i >> 9) % 56;
    int b = i / (56 * 512);
    int idx = (p < HOFF) ? p : (p + 2000);    // [0,4) or [2004,2056)
    hT[(size_t)(b * TP_H + idx) * BN_ + c] = 0;
}

// ---------------------------------------------------------------------------
// K5: GEMM1.  D[o][t] = sum_c W1b[o][c] * xbT[b][t][c];  h = relu(D + bias2[o])
//     128x128 tile, 4 waves (2x2), each wave 4x4 MFMA 16x16x32 subtiles.
//     Epilogue stores hT[b][t+HOFF][o] (4 consecutive o per lane -> 8B stores).
// ---------------------------------------------------------------------------
__global__ __launch_bounds__(256) void k_gemm1(
    const u16* __restrict__ W1b, const u16* __restrict__ xbT,
    const float* __restrict__ bias2, u16* __restrict__ hT)
{
    __shared__ u16 As[128 * 40];   // A: rows m=o, 32 k + pad 8
    __shared__ u16 Bs[128 * 40];   // B: rows n=t
    int tid = threadIdx.x;
    int t0 = blockIdx.x * 128;
    int o0 = blockIdx.y * 128;
    int b  = blockIdx.z;
    int lane = tid & 63, wv = tid >> 6;
    int m_off = (wv & 1) * 64, n_off = (wv >> 1) * 64;
    int lr = lane & 15, q8 = (lane >> 4) * 8;
    f32x4 zz = {0.f, 0.f, 0.f, 0.f};
    f32x4 acc[4][4];
#pragma unroll
    for (int m = 0; m < 4; m++)
#pragma unroll
        for (int n = 0; n < 4; n++) acc[m][n] = zz;

    const u16* Ag = W1b + (size_t)o0 * CIN_;
    const u16* Bg = xbT + (size_t)(b * TP_X + t0) * CIN_;

    for (int kc = 0; kc < CIN_; kc += 32) {
#pragma unroll
        for (int i = 0; i < 2; i++) {
            int q = tid + 256 * i;            // 512 16B chunks per operand
            int row = q >> 2, c16 = (q & 3) * 8;
            u16x8 va = *reinterpret_cast<const u16x8*>(Ag + (size_t)row * CIN_ + kc + c16);
            u16x8 vb = *reinterpret_cast<const u16x8*>(Bg + (size_t)row * CIN_ + kc + c16);
            *reinterpret_cast<u16x8*>(&As[row * 40 + c16]) = va;
            *reinterpret_cast<u16x8*>(&Bs[row * 40 + c16]) = vb;
        }
        __syncthreads();
        bf16x8 af[4], bf[4];
#pragma unroll
        for (int m = 0; m < 4; m++)
            af[m] = *reinterpret_cast<const bf16x8*>(&As[(m_off + m * 16 + lr) * 40 + q8]);
#pragma unroll
        for (int n = 0; n < 4; n++)
            bf[n] = *reinterpret_cast<const bf16x8*>(&Bs[(n_off + n * 16 + lr) * 40 + q8]);
#pragma unroll
        for (int m = 0; m < 4; m++)
#pragma unroll
            for (int n = 0; n < 4; n++)
                acc[m][n] = __builtin_amdgcn_mfma_f32_16x16x32_bf16(af[m], bf[n], acc[m][n], 0, 0, 0);
        __syncthreads();
    }

    int qr = (lane >> 4) * 4;
#pragma unroll
    for (int m = 0; m < 4; m++) {
        int o = o0 + m_off + m * 16 + qr;     // 4 consecutive o (regs)
        f32x4 bb = *reinterpret_cast<const f32x4*>(bias2 + o);
#pragma unroll
        for (int n = 0; n < 4; n++) {
            int t = t0 + n_off + n * 16 + lr;
            if (t < T_) {
                f32x4 v = acc[m][n];
                u16x4 r;
                r.x = f2b(fmaxf(v.x + bb.x, 0.f));
                r.y = f2b(fmaxf(v.y + bb.y, 0.f));
                r.z = f2b(fmaxf(v.z + bb.z, 0.f));
                r.w = f2b(fmaxf(v.w + bb.w, 0.f));
                *reinterpret_cast<u16x4*>(hT + (size_t)(b * TP_H + t + HOFF) * BN_ + o) = r;
            }
        }
    }
}

// ---------------------------------------------------------------------------
// K6: conv branches as 9 shifted GEMMs.
//     D[t][o] = sum_tap sum_c hT[b][t + d*(tap-1)][c] * wb[n][tap][o][c]
//     A-operand = hT rows (m=t), B-operand = wb rows (n=o).
//     C/D: lane holds 4 consecutive t at fixed o -> 8B stores to f[n][b][o][t].
// ---------------------------------------------------------------------------
__global__ __launch_bounds__(256) void k_conv(
    const u16* __restrict__ hT, const u16* __restrict__ wb, u16* __restrict__ f)
{
    __shared__ u16 As[128 * 40];   // rows m=t
    __shared__ u16 Bs[128 * 40];   // rows n=o
    int tid = threadIdx.x;
    int t0 = blockIdx.x * 128;
    int o0 = blockIdx.y * 128;
    int nb = blockIdx.z;
    int n = nb >> 4, b = nb & 15;
    int d = n + 1;
    int lane = tid & 63, wv = tid >> 6;
    int m_off = (wv & 1) * 64, n_off = (wv >> 1) * 64;
    int lr = lane & 15, q8 = (lane >> 4) * 8;
    f32x4 zz = {0.f, 0.f, 0.f, 0.f};
    f32x4 acc[4][4];
#pragma unroll
    for (int m = 0; m < 4; m++)
#pragma unroll
        for (int nn = 0; nn < 4; nn++) acc[m][nn] = zz;

    for (int tap = 0; tap < 3; tap++) {
        int sh = d * (tap - 1);
        const u16* Ag = hT + (size_t)(b * TP_H + t0 + sh + HOFF) * BN_;
        const u16* Bg = wb + (size_t)((n * 3 + tap) * OUT_ + o0) * BN_;
        for (int kc = 0; kc < BN_; kc += 32) {
#pragma unroll
            for (int i = 0; i < 2; i++) {
                int q = tid + 256 * i;
                int row = q >> 2, c16 = (q & 3) * 8;
                u16x8 va = *reinterpret_cast<const u16x8*>(Ag + (size_t)row * BN_ + kc + c16);
                u16x8 vb = *reinterpret_cast<const u16x8*>(Bg + (size_t)row * BN_ + kc + c16);
                *reinterpret_cast<u16x8*>(&As[row * 40 + c16]) = va;
                *reinterpret_cast<u16x8*>(&Bs[row * 40 + c16]) = vb;
            }
            __syncthreads();
            bf16x8 af[4], bf[4];
#pragma unroll
            for (int m = 0; m < 4; m++)
                af[m] = *reinterpret_cast<const bf16x8*>(&As[(m_off + m * 16 + lr) * 40 + q8]);
#pragma unroll
            for (int nn = 0; nn < 4; nn++)
                bf[nn] = *reinterpret_cast<const bf16x8*>(&Bs[(n_off + nn * 16 + lr) * 40 + q8]);
#pragma unroll
            for (int m = 0; m < 4; m++)
#pragma unroll
                for (int nn = 0; nn < 4; nn++)
                    acc[m][nn] = __builtin_amdgcn_mfma_f32_16x16x32_bf16(af[m], bf[nn], acc[m][nn], 0, 0, 0);
            __syncthreads();
        }
    }

    int qr = (lane >> 4) * 4;
#pragma unroll
    for (int m = 0; m < 4; m++) {
        int t = t0 + m_off + m * 16 + qr;     // 4 consecutive t (regs)
#pragma unroll
        for (int nn = 0; nn < 4; nn++) {
            int o = o0 + n_off + nn * 16 + lr;
            f32x4 v = acc[m][nn];
            u16* dst = f + ((size_t)(n * B_ + b) * OUT_ + o) * T_ + t;
            if (t + 3 < T_) {
                u16x4 r;
                r.x = f2b(v.x); r.y = f2b(v.y); r.z = f2b(v.z); r.w = f2b(v.w);
                *reinterpret_cast<u16x4*>(dst) = r;
            } else {
                if (t + 0 < T_) dst[0] = f2b(v.x);
                if (t + 1 < T_) dst[1] = f2b(v.y);
                if (t + 2 < T_) dst[2] = f2b(v.z);
                if (t + 3 < T_) dst[3] = f2b(v.w);
            }
        }
    }
}

// ---------------------------------------------------------------------------
// K7: per-(b,o) high-order stats over t (fp64 raw moments -> central)
// ---------------------------------------------------------------------------
__global__ __launch_bounds__(256) void k_stats(
    const u16* __restrict__ f, float* __restrict__ stats)
{
    int bo = blockIdx.x;          // b*512 + o
    int tid = threadIdx.x;
    const size_t stride = (size_t)B_ * OUT_ * T_;
    const u16* p0 = f + (size_t)bo * T_;
    const u16* p1 = p0 + stride;
    const u16* p2 = p1 + stride;
    double s1 = 0, s2 = 0, s3 = 0, s4 = 0;
    for (int t = tid; t < T_; t += 256) {
        float v = b2f(p0[t]) + b2f(p1[t]) + b2f(p2[t]);
        double dd = (double)v, d2 = dd * dd;
        s1 += dd; s2 += d2; s3 += d2 * dd; s4 += d2 * d2;
    }
    for (int off = 32; off > 0; off >>= 1) {
        s1 += __shfl_down(s1, off);
        s2 += __shfl_down(s2, off);
        s3 += __shfl_down(s3, off);
        s4 += __shfl_down(s4, off);
    }
    __shared__ double red[4][4];
    int lane = tid & 63, wv = tid >> 6;
    if (lane == 0) { red[wv][0] = s1; red[wv][1] = s2; red[wv][2] = s3; red[wv][3] = s4; }
    __syncthreads();
    if (tid == 0) {
        double a1 = 0, a2 = 0, a3 = 0, a4 = 0;
        for (int w = 0; w < 4; w++) { a1 += red[w][0]; a2 += red[w][1]; a3 += red[w][2]; a4 += red[w][3]; }
        const double Tn = (double)T_;
        double m1 = a1 / Tn, m2 = a2 / Tn, m3 = a3 / Tn, m4 = a4 / Tn;
        double c2 = m2 - m1 * m1; if (c2 < 0) c2 = 0;
        double stdv = sqrt(c2 * (Tn / (Tn - 1.0)));
        double sc = stdv > 0.01 ? stdv : 0.01;
        double c3 = m3 - 3.0 * m1 * m2 + 2.0 * m1 * m1 * m1;
        double c4 = m4 - 4.0 * m1 * m3 + 6.0 * m1 * m1 * m2 - 3.0 * m1 * m1 * m1 * m1;
        int b = bo >> 9, o = bo & 511;
        float* sp = stats + (size_t)b * 2048;
        sp[o]        = (float)m1;
        sp[512 + o]  = (float)stdv;
        sp[1024 + o] = (float)(c3 / (sc * sc * sc));
        sp[1536 + o] = (float)(c4 / (sc * sc * sc * sc));
    }
}

// ---------------------------------------------------------------------------
// K8: z[b][r] = stats[b] . sel_W1[r] + sel_b1[r]
// ---------------------------------------------------------------------------
__global__ __launch_bounds__(256) void k_sel1(
    const float* __restrict__ stats, const float* __restrict__ W1s,
    const float* __restrict__ b1s, float* __restrict__ z)
{
    int b = blockIdx.x, tid = threadIdx.x;
    __shared__ float st[2048];
    for (int j = tid; j < 2048; j += 256) st[j] = stats[b * 2048 + j];
    __syncthreads();
    for (int r = tid; r < 512; r += 256) {
        const float* wp = W1s + (size_t)r * 2048;
        float acc = b1s[r];
        for (int j = 0; j < 2048; j += 4) {
            float4 w = *reinterpret_cast<const float4*>(wp + j);
            acc += st[j] * w.x + st[j + 1] * w.y + st[j + 2] * w.z + st[j + 3] * w.w;
        }
        z[b * 512 + r] = acc;
    }
}

// ---------------------------------------------------------------------------
// K9: s[b][n][c] = softmax_n( z[b] . sel_W2[n][c] + sel_b2[n][c] )
// ---------------------------------------------------------------------------
__global__ __launch_bounds__(256) void k_sel2(
    const float* __restrict__ z, const float* __restrict__ W2s,
    const float* __restrict__ b2s, float* __restrict__ s)
{
    int b = blockIdx.x, tid = threadIdx.x;
    __shared__ float zl[512];
    for (int j = tid; j < 512; j += 256) zl[j] = z[b * 512 + j];
    __syncthreads();
    for (int c = tid; c < 512; c += 256) {
        float a[3];
#pragma unroll
        for (int n = 0; n < 3; n++) {
            const float* wp = W2s + (size_t)(n * 512 + c) * 512;
            float acc = b2s[n * 512 + c];
            for (int r = 0; r < 512; r += 4) {
                float4 w = *reinterpret_cast<const float4*>(wp + r);
                acc += zl[r] * w.x + zl[r + 1] * w.y + zl[r + 2] * w.z + zl[r + 3] * w.w;
            }
            a[n] = acc;
        }
        float mx = fmaxf(a[0], fmaxf(a[1], a[2]));
        float e0 = expf(a[0] - mx), e1 = expf(a[1] - mx), e2 = expf(a[2] - mx);
        float inv = 1.f / (e0 + e1 + e2);
        s[(b * 3 + 0) * 512 + c] = e0 * inv;
        s[(b * 3 + 1) * 512 + c] = e1 * inv;
        s[(b * 3 + 2) * 512 + c] = e2 * inv;
    }
}

// ---------------------------------------------------------------------------
// K10: out[b][o][t] = sum_n s[b][n][o] * f[n][b][o][t]
// ---------------------------------------------------------------------------
__global__ __launch_bounds__(256) void k_final(
    const u16* __restrict__ f, const float* __restrict__ s, float* __restrict__ out)
{
    int id = blockIdx.x * 256 + threadIdx.x;   // 16*512*250 threads, 8 t each
    int row = id / 250;                         // b*512 + o
    int t = (id % 250) * 8;
    int b = row >> 9, o = row & 511;
    const size_t stride = (size_t)B_ * OUT_ * T_;
    size_t base = (size_t)row * T_ + t;
    float s0 = s[(b * 3 + 0) * 512 + o];
    float s1 = s[(b * 3 + 1) * 512 + o];
    float s2 = s[(b * 3 + 2) * 512 + o];
    u16x8 a0 = *reinterpret_cast<const u16x8*>(f + base);
    u16x8 a1 = *reinterpret_cast<const u16x8*>(f + stride + base);
    u16x8 a2 = *reinterpret_cast<const u16x8*>(f + 2 * stride + base);
    float4 r0, r1;
    r0.x = s0 * b2f(a0[0]) + s1 * b2f(a1[0]) + s2 * b2f(a2[0]);
    r0.y = s0 * b2f(a0[1]) + s1 * b2f(a1[1]) + s2 * b2f(a2[1]);
    r0.z = s0 * b2f(a0[2]) + s1 * b2f(a1[2]) + s2 * b2f(a2[2]);
    r0.w = s0 * b2f(a0[3]) + s1 * b2f(a1[3]) + s2 * b2f(a2[3]);
    r1.x = s0 * b2f(a0[4]) + s1 * b2f(a1[4]) + s2 * b2f(a2[4]);
    r1.y = s0 * b2f(a0[5]) + s1 * b2f(a1[5]) + s2 * b2f(a2[5]);
    r1.z = s0 * b2f(a0[6]) + s1 * b2f(a1[6]) + s2 * b2f(a2[6]);
    r1.w = s0 * b2f(a0[7]) + s1 * b2f(a1[7]) + s2 * b2f(a2[7]);
    *reinterpret_cast<float4*>(out + base)     = r0;
    *reinterpret_cast<float4*>(out + base + 4) = r1;
}

// ---------------------------------------------------------------------------
extern "C" void kernel_launch(void* const* d_in, const int* in_sizes, int n_in,
                              void* d_out, int out_size, void* d_ws, size_t ws_size,
                              hipStream_t stream)
{
    const float* x     = (const float*)d_in[0];
    const float* bn1g  = (const float*)d_in[1];
    const float* bn1b  = (const float*)d_in[2];
    const float* bn1m  = (const float*)d_in[3];
    const float* bn1v  = (const float*)d_in[4];
    const float* W1    = (const float*)d_in[5];
    const float* bn2g  = (const float*)d_in[6];
    const float* bn2b  = (const float*)d_in[7];
    const float* bn2m  = (const float*)d_in[8];
    const float* bn2v  = (const float*)d_in[9];
    const float* convw = (const float*)d_in[10];
    const float* selW1 = (const float*)d_in[11];
    const float* selb1 = (const float*)d_in[12];
    const float* selW2 = (const float*)d_in[13];
    const float* selb2 = (const float*)d_in[14];
    float* out = (float*)d_out;

    char* ws = (char*)d_ws;
    u16*   xbT   = (u16*)(ws);                       // 16*2048*1024*2 = 67,108,864
    u16*   hT    = (u16*)(ws + 67108864);            // 16*2056* 512*2 = 33,685,504
    u16*   W1b   = (u16*)(ws + 100794368);           // 512*1024*2     =  1,048,576
    float* bias2 = (float*)(ws + 101842944);         // 512*4          =      2,048
    u16*   wb    = (u16*)(ws + 101844992);           // 9*512*512*2    =  4,718,592
    u16*   fbuf  = (u16*)(ws + 106563584);           // 3*16*512*2000*2= 98,304,000
    float* stats = (float*)(ws + 204867584);         // 16*2048*4
    float* zbuf  = (float*)(ws + 204998656);         // 16*512*4
    float* sbuf  = (float*)(ws + 205031424);         // 16*3*512*4

    k_prep_x  <<<dim3(64, 32, 16), 256, 0, stream>>>(x, bn1g, bn1b, bn1m, bn1v, xbT);
    k_prep_w1 <<<512,  256, 0, stream>>>(W1, bn2g, bn2b, bn2m, bn2v, W1b, bias2);
    k_prep_wc <<<3072, 256, 0, stream>>>(convw, wb);
    k_zero_hpad<<<1792, 256, 0, stream>>>(hT);
    k_gemm1   <<<dim3(16, 4, 16), 256, 0, stream>>>(W1b, xbT, bias2, hT);
    k_conv    <<<dim3(16, 4, 48), 256, 0, stream>>>(hT, wb, fbuf);
    k_stats   <<<8192, 256, 0, stream>>>(fbuf, stats);
    k_sel1    <<<16, 256, 0, stream>>>(stats, selW1, selb1, zbuf);
    k_sel2    <<<16, 256, 0, stream>>>(zbuf, selW2, selb2, sbuf);
    k_final   <<<8000, 256, 0, stream>>>(fbuf, sbuf, out);
}

// Round 2
// 565.073 us; speedup vs baseline: 1.3814x; 1.3814x over previous
//
#include <hip/hip_runtime.h>
#include <hip/hip_bf16.h>

#define B_    16
#define CIN_  1024
#define T_    2000
#define BN_   512
#define OUT_  512
#define NBR_  3
#define TP_X  2048   // xbT padded t-extent
#define TP_H  2056   // hT padded t-extent (index = t + HOFF)
#define HOFF  4

typedef float  f32x4  __attribute__((ext_vector_type(4)));
typedef __bf16 bf16x8 __attribute__((ext_vector_type(8)));
typedef unsigned short u16;
typedef u16 u16x4 __attribute__((ext_vector_type(4)));
typedef u16 u16x8 __attribute__((ext_vector_type(8)));

static __device__ __forceinline__ float b2f(u16 u) {
    union { float f; unsigned int i; } v; v.i = ((unsigned int)u) << 16; return v.f;
}
static __device__ __forceinline__ u16 f2b(float f) {
    __hip_bfloat16 h = __float2bfloat16(f);   // RNE
    u16 r; __builtin_memcpy(&r, &h, 2); return r;
}
// async global->LDS, 16B per lane; LDS dest = uniform base + lane*16
static __device__ __forceinline__ void gld16(const u16* g, u16* l) {
    __builtin_amdgcn_global_load_lds(
        (const __attribute__((address_space(1))) unsigned int*)g,
        (__attribute__((address_space(3))) unsigned int*)l, 16, 0, 0);
}

// ---------------------------------------------------------------------------
// K1: x[b,c,t] --BN1+ReLU--> bf16, transposed to xbT[b][t][c], t padded to 2048
// ---------------------------------------------------------------------------
__global__ __launch_bounds__(256) void k_prep_x(
    const float* __restrict__ x, const float* __restrict__ g,
    const float* __restrict__ be, const float* __restrict__ mu,
    const float* __restrict__ va, u16* __restrict__ xbT)
{
    __shared__ float tile[32][33];
    int b = blockIdx.z, c0 = blockIdx.y * 32, t0 = blockIdx.x * 32;
    int tid = threadIdx.x;
    int cl = tid >> 3, tt = (tid & 7) * 4;
    int c = c0 + cl;
    float inv = g[c] / sqrtf(va[c] + 1e-5f);
    float bia = be[c] - mu[c] * inv;
    int t = t0 + tt;
    float y0 = 0.f, y1 = 0.f, y2 = 0.f, y3 = 0.f;
    if (t < T_) {
        float4 v = *reinterpret_cast<const float4*>(x + (size_t)(b * CIN_ + c) * T_ + t);
        y0 = fmaxf(v.x * inv + bia, 0.f);
        y1 = fmaxf(v.y * inv + bia, 0.f);
        y2 = fmaxf(v.z * inv + bia, 0.f);
        y3 = fmaxf(v.w * inv + bia, 0.f);
    }
    tile[tt + 0][cl] = y0; tile[tt + 1][cl] = y1;
    tile[tt + 2][cl] = y2; tile[tt + 3][cl] = y3;
    __syncthreads();
    int tl = tid >> 3, c8 = (tid & 7) * 4;
    u16x4 o;
    o.x = f2b(tile[tl][c8 + 0]);
    o.y = f2b(tile[tl][c8 + 1]);
    o.z = f2b(tile[tl][c8 + 2]);
    o.w = f2b(tile[tl][c8 + 3]);
    *reinterpret_cast<u16x4*>(xbT + (size_t)(b * TP_X + t0 + tl) * CIN_ + c0 + c8) = o;
}

// ---------------------------------------------------------------------------
// K2: W1b[o][c] = bf16(W1[o][c] * inv2[o]);  bias2[o] = beta2 - mean2*inv2
// ---------------------------------------------------------------------------
__global__ __launch_bounds__(256) void k_prep_w1(
    const float* __restrict__ W1, const float* __restrict__ g,
    const float* __restrict__ be, const float* __restrict__ mu,
    const float* __restrict__ va, u16* __restrict__ W1b, float* __restrict__ bias2)
{
    int i = blockIdx.x * 256 + threadIdx.x;
    int o = i >> 8;
    int c = (i & 255) * 4;
    float inv = g[o] / sqrtf(va[o] + 1e-5f);
    if (c == 0) bias2[o] = be[o] - mu[o] * inv;
    float4 w = *reinterpret_cast<const float4*>(W1 + (size_t)o * CIN_ + c);
    u16x4 r;
    r.x = f2b(w.x * inv); r.y = f2b(w.y * inv);
    r.z = f2b(w.z * inv); r.w = f2b(w.w * inv);
    *reinterpret_cast<u16x4*>(W1b + (size_t)o * CIN_ + c) = r;
}

// ---------------------------------------------------------------------------
// K3: conv_w[n][o][c][k] -> wb[n][k][o][c] bf16
// ---------------------------------------------------------------------------
__global__ __launch_bounds__(256) void k_prep_wc(
    const float* __restrict__ cw, u16* __restrict__ wb)
{
    int i = blockIdx.x * 256 + threadIdx.x;
    if (i >= NBR_ * OUT_ * BN_) return;
    const float* p = cw + (size_t)i * 3;
    int c = i & 511;
    int o = (i >> 9) & 511;
    int n = i >> 18;
#pragma unroll
    for (int k = 0; k < 3; k++)
        wb[((size_t)(n * 3 + k) * OUT_ + o) * BN_ + c] = f2b(p[k]);
}

// ---------------------------------------------------------------------------
// K4: zero hT pad rows (idx [0,4) and [2004,2056))
// ---------------------------------------------------------------------------
__global__ __launch_bounds__(256) void k_zero_hpad(u16* __restrict__ hT)
{
    int i = blockIdx.x * 256 + threadIdx.x;
    if (i >= B_ * 56 * BN_) return;
    int c = i & 511;
    int p = (i >> 9) % 56;
    int b = i / (56 * 512);
    int idx = (p < HOFF) ? p : (p + 2000);
    hT[(size_t)(b * TP_H + idx) * BN_ + c] = 0;
}

// ---------------------------------------------------------------------------
// K5: GEMM1.  D[o][t] = sum_c W1b[o][c] * xbT[b][t][c];  h = relu(D + bias2[o])
//     global_load_lds width=16 staging; source-side XOR swizzle so unpadded
//     64B LDS rows read back 2-way (free) instead of 8-way conflicted.
// ---------------------------------------------------------------------------
__global__ __launch_bounds__(256) void k_gemm1(
    const u16* __restrict__ W1b, const u16* __restrict__ xbT,
    const float* __restrict__ bias2, u16* __restrict__ hT)
{
    __shared__ u16 As[128 * 32];   // rows m=o, 32 k, unpadded (64B rows)
    __shared__ u16 Bs[128 * 32];   // rows n=t
    int tid = threadIdx.x;
    int t0 = blockIdx.x * 128;
    int o0 = blockIdx.y * 128;
    int b  = blockIdx.z;
    int lane = tid & 63, wv = tid >> 6;
    int m_off = (wv & 1) * 64, n_off = (wv >> 1) * 64;
    int lr = lane & 15, g = lane >> 4;

    // staging: slot s -> (row=s>>2, chunk g=(s&3)^((s>>3)&3)); LDS gets chunk-
    // swizzled image; each wave stages 2x64 slots per operand.
    int s0 = wv * 128 + lane, s1 = s0 + 64;
    size_t ga0 = (size_t)(s0 >> 2) * CIN_ + (((s0 & 3) ^ ((s0 >> 3) & 3)) * 8);
    size_t ga1 = (size_t)(s1 >> 2) * CIN_ + (((s1 & 3) ^ ((s1 >> 3) & 3)) * 8);
    u16* lA0 = As + (size_t)(wv * 128) * 8; u16* lA1 = lA0 + 512;
    u16* lB0 = Bs + (size_t)(wv * 128) * 8; u16* lB1 = lB0 + 512;

    // fragment read offsets (u16 units), loop-invariant
    int sw = (g ^ ((lr >> 1) & 3)) * 8;
    int fA[4], fB[4];
#pragma unroll
    for (int m = 0; m < 4; m++) fA[m] = (m_off + m * 16 + lr) * 32 + sw;
#pragma unroll
    for (int n = 0; n < 4; n++) fB[n] = (n_off + n * 16 + lr) * 32 + sw;

    f32x4 zz = {0.f, 0.f, 0.f, 0.f};
    f32x4 acc[4][4];
#pragma unroll
    for (int m = 0; m < 4; m++)
#pragma unroll
        for (int n = 0; n < 4; n++) acc[m][n] = zz;

    const u16* Ag = W1b + (size_t)o0 * CIN_;
    const u16* Bg = xbT + (size_t)(b * TP_X + t0) * CIN_;

    for (int kc = 0; kc < CIN_; kc += 32) {
        gld16(Ag + ga0 + kc, lA0);
        gld16(Ag + ga1 + kc, lA1);
        gld16(Bg + ga0 + kc, lB0);
        gld16(Bg + ga1 + kc, lB1);
        __syncthreads();
        bf16x8 af[4], bfr[4];
#pragma unroll
        for (int m = 0; m < 4; m++) af[m] = *reinterpret_cast<const bf16x8*>(As + fA[m]);
#pragma unroll
        for (int n = 0; n < 4; n++) bfr[n] = *reinterpret_cast<const bf16x8*>(Bs + fB[n]);
#pragma unroll
        for (int m = 0; m < 4; m++)
#pragma unroll
            for (int n = 0; n < 4; n++)
                acc[m][n] = __builtin_amdgcn_mfma_f32_16x16x32_bf16(af[m], bfr[n], acc[m][n], 0, 0, 0);
        __syncthreads();
    }

    int qr = (lane >> 4) * 4;
#pragma unroll
    for (int m = 0; m < 4; m++) {
        int o = o0 + m_off + m * 16 + qr;
        f32x4 bb = *reinterpret_cast<const f32x4*>(bias2 + o);
#pragma unroll
        for (int n = 0; n < 4; n++) {
            int t = t0 + n_off + n * 16 + lr;
            if (t < T_) {
                f32x4 v = acc[m][n];
                u16x4 r;
                r.x = f2b(fmaxf(v.x + bb.x, 0.f));
                r.y = f2b(fmaxf(v.y + bb.y, 0.f));
                r.z = f2b(fmaxf(v.z + bb.z, 0.f));
                r.w = f2b(fmaxf(v.w + bb.w, 0.f));
                *reinterpret_cast<u16x4*>(hT + (size_t)(b * TP_H + t + HOFF) * BN_ + o) = r;
            }
        }
    }
}

// ---------------------------------------------------------------------------
// K6: conv branches as 9 shifted GEMMs (same staging scheme, ldK = 512)
// ---------------------------------------------------------------------------
__global__ __launch_bounds__(256) void k_conv(
    const u16* __restrict__ hT, const u16* __restrict__ wb, u16* __restrict__ f)
{
    __shared__ u16 As[128 * 32];   // rows m=t
    __shared__ u16 Bs[128 * 32];   // rows n=o
    int tid = threadIdx.x;
    int t0 = blockIdx.x * 128;
    int o0 = blockIdx.y * 128;
    int nb = blockIdx.z;
    int n = nb >> 4, b = nb & 15;
    int d = n + 1;
    int lane = tid & 63, wv = tid >> 6;
    int m_off = (wv & 1) * 64, n_off = (wv >> 1) * 64;
    int lr = lane & 15, g = lane >> 4;

    int s0 = wv * 128 + lane, s1 = s0 + 64;
    size_t ga0 = (size_t)(s0 >> 2) * BN_ + (((s0 & 3) ^ ((s0 >> 3) & 3)) * 8);
    size_t ga1 = (size_t)(s1 >> 2) * BN_ + (((s1 & 3) ^ ((s1 >> 3) & 3)) * 8);
    u16* lA0 = As + (size_t)(wv * 128) * 8; u16* lA1 = lA0 + 512;
    u16* lB0 = Bs + (size_t)(wv * 128) * 8; u16* lB1 = lB0 + 512;

    int sw = (g ^ ((lr >> 1) & 3)) * 8;
    int fA[4], fB[4];
#pragma unroll
    for (int m = 0; m < 4; m++) fA[m] = (m_off + m * 16 + lr) * 32 + sw;
#pragma unroll
    for (int nn = 0; nn < 4; nn++) fB[nn] = (n_off + nn * 16 + lr) * 32 + sw;

    f32x4 zz = {0.f, 0.f, 0.f, 0.f};
    f32x4 acc[4][4];
#pragma unroll
    for (int m = 0; m < 4; m++)
#pragma unroll
        for (int nn = 0; nn < 4; nn++) acc[m][nn] = zz;

    for (int tap = 0; tap < 3; tap++) {
        const u16* Ag = hT + (size_t)(b * TP_H + t0 + d * (tap - 1) + HOFF) * BN_;
        const u16* Bg = wb + (size_t)((n * 3 + tap) * OUT_ + o0) * BN_;
        for (int kc = 0; kc < BN_; kc += 32) {
            gld16(Ag + ga0 + kc, lA0);
            gld16(Ag + ga1 + kc, lA1);
            gld16(Bg + ga0 + kc, lB0);
            gld16(Bg + ga1 + kc, lB1);
            __syncthreads();
            bf16x8 af[4], bfr[4];
#pragma unroll
            for (int m = 0; m < 4; m++) af[m] = *reinterpret_cast<const bf16x8*>(As + fA[m]);
#pragma unroll
            for (int nn = 0; nn < 4; nn++) bfr[nn] = *reinterpret_cast<const bf16x8*>(Bs + fB[nn]);
#pragma unroll
            for (int m = 0; m < 4; m++)
#pragma unroll
                for (int nn = 0; nn < 4; nn++)
                    acc[m][nn] = __builtin_amdgcn_mfma_f32_16x16x32_bf16(af[m], bfr[nn], acc[m][nn], 0, 0, 0);
            __syncthreads();
        }
    }

    int qr = (lane >> 4) * 4;
#pragma unroll
    for (int m = 0; m < 4; m++) {
        int t = t0 + m_off + m * 16 + qr;     // 4 consecutive t per lane
#pragma unroll
        for (int nn = 0; nn < 4; nn++) {
            int o = o0 + n_off + nn * 16 + lr;
            f32x4 v = acc[m][nn];
            u16* dst = f + ((size_t)(n * B_ + b) * OUT_ + o) * T_ + t;
            if (t + 3 < T_) {
                u16x4 r;
                r.x = f2b(v.x); r.y = f2b(v.y); r.z = f2b(v.z); r.w = f2b(v.w);
                *reinterpret_cast<u16x4*>(dst) = r;
            } else {
                if (t + 0 < T_) dst[0] = f2b(v.x);
                if (t + 1 < T_) dst[1] = f2b(v.y);
                if (t + 2 < T_) dst[2] = f2b(v.z);
                if (t + 3 < T_) dst[3] = f2b(v.w);
            }
        }
    }
}

// ---------------------------------------------------------------------------
// K7: per-(b,o) high-order stats over t (fp64 raw moments -> central)
// ---------------------------------------------------------------------------
__global__ __launch_bounds__(256) void k_stats(
    const u16* __restrict__ f, float* __restrict__ stats)
{
    int bo = blockIdx.x;
    int tid = threadIdx.x;
    const size_t stride = (size_t)B_ * OUT_ * T_;
    const u16* p0 = f + (size_t)bo * T_;
    const u16* p1 = p0 + stride;
    const u16* p2 = p1 + stride;
    double s1 = 0, s2 = 0, s3 = 0, s4 = 0;
    for (int t = tid; t < T_; t += 256) {
        float v = b2f(p0[t]) + b2f(p1[t]) + b2f(p2[t]);
        double dd = (double)v, d2 = dd * dd;
        s1 += dd; s2 += d2; s3 += d2 * dd; s4 += d2 * d2;
    }
    for (int off = 32; off > 0; off >>= 1) {
        s1 += __shfl_down(s1, off);
        s2 += __shfl_down(s2, off);
        s3 += __shfl_down(s3, off);
        s4 += __shfl_down(s4, off);
    }
    __shared__ double red[4][4];
    int lane = tid & 63, wv = tid >> 6;
    if (lane == 0) { red[wv][0] = s1; red[wv][1] = s2; red[wv][2] = s3; red[wv][3] = s4; }
    __syncthreads();
    if (tid == 0) {
        double a1 = 0, a2 = 0, a3 = 0, a4 = 0;
        for (int w = 0; w < 4; w++) { a1 += red[w][0]; a2 += red[w][1]; a3 += red[w][2]; a4 += red[w][3]; }
        const double Tn = (double)T_;
        double m1 = a1 / Tn, m2 = a2 / Tn, m3 = a3 / Tn, m4 = a4 / Tn;
        double c2 = m2 - m1 * m1; if (c2 < 0) c2 = 0;
        double stdv = sqrt(c2 * (Tn / (Tn - 1.0)));
        double sc = stdv > 0.01 ? stdv : 0.01;
        double c3 = m3 - 3.0 * m1 * m2 + 2.0 * m1 * m1 * m1;
        double c4 = m4 - 4.0 * m1 * m3 + 6.0 * m1 * m1 * m2 - 3.0 * m1 * m1 * m1 * m1;
        int b = bo >> 9, o = bo & 511;
        float* sp = stats + (size_t)b * 2048;
        sp[o]        = (float)m1;
        sp[512 + o]  = (float)stdv;
        sp[1024 + o] = (float)(c3 / (sc * sc * sc));
        sp[1536 + o] = (float)(c4 / (sc * sc * sc * sc));
    }
}

// ---------------------------------------------------------------------------
// K8: z[b][r] = stats[b] . sel_W1[r] + sel_b1[r]  — one wave per (b,r)
// ---------------------------------------------------------------------------
__global__ __launch_bounds__(256) void k_sel1(
    const float* __restrict__ stats, const float* __restrict__ W1s,
    const float* __restrict__ b1s, float* __restrict__ z)
{
    int gid = blockIdx.x * 4 + (threadIdx.x >> 6);   // b*512 + r
    int lane = threadIdx.x & 63;
    int b = gid >> 9, r = gid & 511;
    const float4* wp = reinterpret_cast<const float4*>(W1s + (size_t)r * 2048 + lane * 32);
    const float4* sp = reinterpret_cast<const float4*>(stats + (size_t)b * 2048 + lane * 32);
    float acc = 0.f;
#pragma unroll
    for (int j = 0; j < 8; j++) {
        float4 w = wp[j], s = sp[j];
        acc += w.x * s.x + w.y * s.y + w.z * s.z + w.w * s.w;
    }
#pragma unroll
    for (int off = 32; off > 0; off >>= 1) acc += __shfl_down(acc, off);
    if (lane == 0) z[gid] = acc + b1s[r];
}

// ---------------------------------------------------------------------------
// K9: s[b][n][c] = softmax_n( z[b] . sel_W2[n][c] + sel_b2[n][c] ) — wave/(b,c)
// ---------------------------------------------------------------------------
__global__ __launch_bounds__(256) void k_sel2(
    const float* __restrict__ z, const float* __restrict__ W2s,
    const float* __restrict__ b2s, float* __restrict__ s)
{
    int gid = blockIdx.x * 4 + (threadIdx.x >> 6);   // b*512 + c
    int lane = threadIdx.x & 63;
    int b = gid >> 9, c = gid & 511;
    const float4* zp = reinterpret_cast<const float4*>(z + (size_t)b * 512 + lane * 8);
    float4 z0 = zp[0], z1 = zp[1];
    float a[3];
#pragma unroll
    for (int n = 0; n < 3; n++) {
        const float4* wp = reinterpret_cast<const float4*>(W2s + (size_t)(n * 512 + c) * 512 + lane * 8);
        float4 w0 = wp[0], w1 = wp[1];
        float acc = z0.x * w0.x + z0.y * w0.y + z0.z * w0.z + z0.w * w0.w
                  + z1.x * w1.x + z1.y * w1.y + z1.z * w1.z + z1.w * w1.w;
#pragma unroll
        for (int off = 32; off > 0; off >>= 1) acc += __shfl_down(acc, off);
        a[n] = acc + b2s[n * 512 + c];
    }
    if (lane == 0) {
        float mx = fmaxf(a[0], fmaxf(a[1], a[2]));
        float e0 = expf(a[0] - mx), e1 = expf(a[1] - mx), e2 = expf(a[2] - mx);
        float inv = 1.f / (e0 + e1 + e2);
        s[(b * 3 + 0) * 512 + c] = e0 * inv;
        s[(b * 3 + 1) * 512 + c] = e1 * inv;
        s[(b * 3 + 2) * 512 + c] = e2 * inv;
    }
}

// ---------------------------------------------------------------------------
// K10: out[b][o][t] = sum_n s[b][n][o] * f[n][b][o][t]
// ---------------------------------------------------------------------------
__global__ __launch_bounds__(256) void k_final(
    const u16* __restrict__ f, const float* __restrict__ s, float* __restrict__ out)
{
    int id = blockIdx.x * 256 + threadIdx.x;
    int row = id / 250;                         // b*512 + o
    int t = (id % 250) * 8;
    int b = row >> 9, o = row & 511;
    const size_t stride = (size_t)B_ * OUT_ * T_;
    size_t base = (size_t)row * T_ + t;
    float s0 = s[(b * 3 + 0) * 512 + o];
    float s1 = s[(b * 3 + 1) * 512 + o];
    float s2 = s[(b * 3 + 2) * 512 + o];
    u16x8 a0 = *reinterpret_cast<const u16x8*>(f + base);
    u16x8 a1 = *reinterpret_cast<const u16x8*>(f + stride + base);
    u16x8 a2 = *reinterpret_cast<const u16x8*>(f + 2 * stride + base);
    float4 r0, r1;
    r0.x = s0 * b2f(a0[0]) + s1 * b2f(a1[0]) + s2 * b2f(a2[0]);
    r0.y = s0 * b2f(a0[1]) + s1 * b2f(a1[1]) + s2 * b2f(a2[1]);
    r0.z = s0 * b2f(a0[2]) + s1 * b2f(a1[2]) + s2 * b2f(a2[2]);
    r0.w = s0 * b2f(a0[3]) + s1 * b2f(a1[3]) + s2 * b2f(a2[3]);
    r1.x = s0 * b2f(a0[4]) + s1 * b2f(a1[4]) + s2 * b2f(a2[4]);
    r1.y = s0 * b2f(a0[5]) + s1 * b2f(a1[5]) + s2 * b2f(a2[5]);
    r1.z = s0 * b2f(a0[6]) + s1 * b2f(a1[6]) + s2 * b2f(a2[6]);
    r1.w = s0 * b2f(a0[7]) + s1 * b2f(a1[7]) + s2 * b2f(a2[7]);
    *reinterpret_cast<float4*>(out + base)     = r0;
    *reinterpret_cast<float4*>(out + base + 4) = r1;
}

// ---------------------------------------------------------------------------
extern "C" void kernel_launch(void* const* d_in, const int* in_sizes, int n_in,
                              void* d_out, int out_size, void* d_ws, size_t ws_size,
                              hipStream_t stream)
{
    const float* x     = (const float*)d_in[0];
    const float* bn1g  = (const float*)d_in[1];
    const float* bn1b  = (const float*)d_in[2];
    const float* bn1m  = (const float*)d_in[3];
    const float* bn1v  = (const float*)d_in[4];
    const float* W1    = (const float*)d_in[5];
    const float* bn2g  = (const float*)d_in[6];
    const float* bn2b  = (const float*)d_in[7];
    const float* bn2m  = (const float*)d_in[8];
    const float* bn2v  = (const float*)d_in[9];
    const float* convw = (const float*)d_in[10];
    const float* selW1 = (const float*)d_in[11];
    const float* selb1 = (const float*)d_in[12];
    const float* selW2 = (const float*)d_in[13];
    const float* selb2 = (const float*)d_in[14];
    float* out = (float*)d_out;

    char* ws = (char*)d_ws;
    u16*   xbT   = (u16*)(ws);                       // 16*2048*1024*2 = 67,108,864
    u16*   hT    = (u16*)(ws + 67108864);            // 16*2056* 512*2 = 33,685,504
    u16*   W1b   = (u16*)(ws + 100794368);           // 512*1024*2     =  1,048,576
    float* bias2 = (float*)(ws + 101842944);         // 512*4
    u16*   wb    = (u16*)(ws + 101844992);           // 9*512*512*2    =  4,718,592
    u16*   fbuf  = (u16*)(ws + 106563584);           // 3*16*512*2000*2= 98,304,000
    float* stats = (float*)(ws + 204867584);         // 16*2048*4
    float* zbuf  = (float*)(ws + 204998656);         // 16*512*4
    float* sbuf  = (float*)(ws + 205031424);         // 16*3*512*4

    k_prep_x  <<<dim3(64, 32, 16), 256, 0, stream>>>(x, bn1g, bn1b, bn1m, bn1v, xbT);
    k_prep_w1 <<<512,  256, 0, stream>>>(W1, bn2g, bn2b, bn2m, bn2v, W1b, bias2);
    k_prep_wc <<<3072, 256, 0, stream>>>(convw, wb);
    k_zero_hpad<<<1792, 256, 0, stream>>>(hT);
    k_gemm1   <<<dim3(16, 4, 16), 256, 0, stream>>>(W1b, xbT, bias2, hT);
    k_conv    <<<dim3(16, 4, 48), 256, 0, stream>>>(hT, wb, fbuf);
    k_stats   <<<8192, 256, 0, stream>>>(fbuf, stats);
    k_sel1    <<<2048, 256, 0, stream>>>(stats, selW1, selb1, zbuf);
    k_sel2    <<<2048, 256, 0, stream>>>(zbuf, selW2, selb2, sbuf);
    k_final   <<<8000, 256, 0, stream>>>(fbuf, sbuf, out);
}

// Round 3
// 504.731 us; speedup vs baseline: 1.5465x; 1.1196x over previous
//
#include <hip/hip_runtime.h>
#include <hip/hip_bf16.h>

#define B_    16
#define CIN_  1024
#define T_    2000
#define BN_   512
#define OUT_  512
#define NBR_  3
#define TP_X  2048   // xbT padded t-extent
#define TP_H  2064   // hT padded t-extent (index = t + HOFF); 60-row tail pad for halo
#define HOFF  4

typedef float  f32x4  __attribute__((ext_vector_type(4)));
typedef __bf16 bf16x8 __attribute__((ext_vector_type(8)));
typedef unsigned short u16;
typedef u16 u16x4 __attribute__((ext_vector_type(4)));
typedef u16 u16x8 __attribute__((ext_vector_type(8)));

static __device__ __forceinline__ float b2f(u16 u) {
    union { float f; unsigned int i; } v; v.i = ((unsigned int)u) << 16; return v.f;
}
static __device__ __forceinline__ u16 f2b(float f) {
    __hip_bfloat16 h = __float2bfloat16(f);   // RNE
    u16 r; __builtin_memcpy(&r, &h, 2); return r;
}
// async global->LDS, 16B per lane; LDS dest = uniform base + lane*16
static __device__ __forceinline__ void gld16(const u16* g, u16* l) {
    __builtin_amdgcn_global_load_lds(
        (const __attribute__((address_space(1))) unsigned int*)g,
        (__attribute__((address_space(3))) unsigned int*)l, 16, 0, 0);
}

// ---------------------------------------------------------------------------
// K1: x[b,c,t] --BN1+ReLU--> bf16, transposed to xbT[b][t][c], t padded to 2048
// ---------------------------------------------------------------------------
__global__ __launch_bounds__(256) void k_prep_x(
    const float* __restrict__ x, const float* __restrict__ g,
    const float* __restrict__ be, const float* __restrict__ mu,
    const float* __restrict__ va, u16* __restrict__ xbT)
{
    __shared__ float tile[32][33];
    int b = blockIdx.z, c0 = blockIdx.y * 32, t0 = blockIdx.x * 32;
    int tid = threadIdx.x;
    int cl = tid >> 3, tt = (tid & 7) * 4;
    int c = c0 + cl;
    float inv = g[c] / sqrtf(va[c] + 1e-5f);
    float bia = be[c] - mu[c] * inv;
    int t = t0 + tt;
    float y0 = 0.f, y1 = 0.f, y2 = 0.f, y3 = 0.f;
    if (t < T_) {
        float4 v = *reinterpret_cast<const float4*>(x + (size_t)(b * CIN_ + c) * T_ + t);
        y0 = fmaxf(v.x * inv + bia, 0.f);
        y1 = fmaxf(v.y * inv + bia, 0.f);
        y2 = fmaxf(v.z * inv + bia, 0.f);
        y3 = fmaxf(v.w * inv + bia, 0.f);
    }
    tile[tt + 0][cl] = y0; tile[tt + 1][cl] = y1;
    tile[tt + 2][cl] = y2; tile[tt + 3][cl] = y3;
    __syncthreads();
    int tl = tid >> 3, c8 = (tid & 7) * 4;
    u16x4 o;
    o.x = f2b(tile[tl][c8 + 0]);
    o.y = f2b(tile[tl][c8 + 1]);
    o.z = f2b(tile[tl][c8 + 2]);
    o.w = f2b(tile[tl][c8 + 3]);
    *reinterpret_cast<u16x4*>(xbT + (size_t)(b * TP_X + t0 + tl) * CIN_ + c0 + c8) = o;
}

// ---------------------------------------------------------------------------
// K2: W1b[o][c] = bf16(W1[o][c] * inv2[o]);  bias2[o] = beta2 - mean2*inv2
// ---------------------------------------------------------------------------
__global__ __launch_bounds__(256) void k_prep_w1(
    const float* __restrict__ W1, const float* __restrict__ g,
    const float* __restrict__ be, const float* __restrict__ mu,
    const float* __restrict__ va, u16* __restrict__ W1b, float* __restrict__ bias2)
{
    int i = blockIdx.x * 256 + threadIdx.x;
    int o = i >> 8;
    int c = (i & 255) * 4;
    float inv = g[o] / sqrtf(va[o] + 1e-5f);
    if (c == 0) bias2[o] = be[o] - mu[o] * inv;
    float4 w = *reinterpret_cast<const float4*>(W1 + (size_t)o * CIN_ + c);
    u16x4 r;
    r.x = f2b(w.x * inv); r.y = f2b(w.y * inv);
    r.z = f2b(w.z * inv); r.w = f2b(w.w * inv);
    *reinterpret_cast<u16x4*>(W1b + (size_t)o * CIN_ + c) = r;
}

// ---------------------------------------------------------------------------
// K3: conv_w[n][o][c][k] -> wb[n][k][o][c] bf16
// ---------------------------------------------------------------------------
__global__ __launch_bounds__(256) void k_prep_wc(
    const float* __restrict__ cw, u16* __restrict__ wb)
{
    int i = blockIdx.x * 256 + threadIdx.x;
    if (i >= NBR_ * OUT_ * BN_) return;
    const float* p = cw + (size_t)i * 3;
    int c = i & 511;
    int o = (i >> 9) & 511;
    int n = i >> 18;
#pragma unroll
    for (int k = 0; k < 3; k++)
        wb[((size_t)(n * 3 + k) * OUT_ + o) * BN_ + c] = f2b(p[k]);
}

// ---------------------------------------------------------------------------
// K4: zero hT pad rows (idx [0,4) and [2004,2064))
// ---------------------------------------------------------------------------
__global__ __launch_bounds__(256) void k_zero_hpad(u16* __restrict__ hT)
{
    int i = blockIdx.x * 256 + threadIdx.x;
    if (i >= B_ * 64 * BN_) return;
    int c = i & 511;
    int p = (i >> 9) % 64;
    int b = i / (64 * 512);
    int idx = (p < HOFF) ? p : (p + 2000);   // [0,4) or [2004,2064)
    hT[(size_t)(b * TP_H + idx) * BN_ + c] = 0;
}

// ---------------------------------------------------------------------------
// K5: GEMM1.  D[o][t] = sum_c W1b[o][c] * xbT[b][t][c];  h = relu(D + bias2[o])
//     global_load_lds width=16 staging; source-side XOR swizzle (0 conflicts).
// ---------------------------------------------------------------------------
__global__ __launch_bounds__(256) void k_gemm1(
    const u16* __restrict__ W1b, const u16* __restrict__ xbT,
    const float* __restrict__ bias2, u16* __restrict__ hT)
{
    __shared__ u16 As[128 * 32];
    __shared__ u16 Bs[128 * 32];
    int tid = threadIdx.x;
    int t0 = blockIdx.x * 128;
    int o0 = blockIdx.y * 128;
    int b  = blockIdx.z;
    int lane = tid & 63, wv = tid >> 6;
    int m_off = (wv & 1) * 64, n_off = (wv >> 1) * 64;
    int lr = lane & 15, g = lane >> 4;

    int s0 = wv * 128 + lane, s1 = s0 + 64;
    size_t ga0 = (size_t)(s0 >> 2) * CIN_ + (((s0 & 3) ^ ((s0 >> 3) & 3)) * 8);
    size_t ga1 = (size_t)(s1 >> 2) * CIN_ + (((s1 & 3) ^ ((s1 >> 3) & 3)) * 8);
    u16* lA0 = As + (size_t)(wv * 128) * 8; u16* lA1 = lA0 + 512;
    u16* lB0 = Bs + (size_t)(wv * 128) * 8; u16* lB1 = lB0 + 512;

    int sw = (g ^ ((lr >> 1) & 3)) * 8;
    int fA[4], fB[4];
#pragma unroll
    for (int m = 0; m < 4; m++) fA[m] = (m_off + m * 16 + lr) * 32 + sw;
#pragma unroll
    for (int n = 0; n < 4; n++) fB[n] = (n_off + n * 16 + lr) * 32 + sw;

    f32x4 zz = {0.f, 0.f, 0.f, 0.f};
    f32x4 acc[4][4];
#pragma unroll
    for (int m = 0; m < 4; m++)
#pragma unroll
        for (int n = 0; n < 4; n++) acc[m][n] = zz;

    const u16* Ag = W1b + (size_t)o0 * CIN_;
    const u16* Bg = xbT + (size_t)(b * TP_X + t0) * CIN_;

    for (int kc = 0; kc < CIN_; kc += 32) {
        gld16(Ag + ga0 + kc, lA0);
        gld16(Ag + ga1 + kc, lA1);
        gld16(Bg + ga0 + kc, lB0);
        gld16(Bg + ga1 + kc, lB1);
        __syncthreads();
        bf16x8 af[4], bfr[4];
#pragma unroll
        for (int m = 0; m < 4; m++) af[m] = *reinterpret_cast<const bf16x8*>(As + fA[m]);
#pragma unroll
        for (int n = 0; n < 4; n++) bfr[n] = *reinterpret_cast<const bf16x8*>(Bs + fB[n]);
#pragma unroll
        for (int m = 0; m < 4; m++)
#pragma unroll
            for (int n = 0; n < 4; n++)
                acc[m][n] = __builtin_amdgcn_mfma_f32_16x16x32_bf16(af[m], bfr[n], acc[m][n], 0, 0, 0);
        __syncthreads();
    }

    int qr = (lane >> 4) * 4;
#pragma unroll
    for (int m = 0; m < 4; m++) {
        int o = o0 + m_off + m * 16 + qr;
        f32x4 bb = *reinterpret_cast<const f32x4*>(bias2 + o);
#pragma unroll
        for (int n = 0; n < 4; n++) {
            int t = t0 + n_off + n * 16 + lr;
            if (t < T_) {
                f32x4 v = acc[m][n];
                u16x4 r;
                r.x = f2b(fmaxf(v.x + bb.x, 0.f));
                r.y = f2b(fmaxf(v.y + bb.y, 0.f));
                r.z = f2b(fmaxf(v.z + bb.z, 0.f));
                r.w = f2b(fmaxf(v.w + bb.w, 0.f));
                *reinterpret_cast<u16x4*>(hT + (size_t)(b * TP_H + t + HOFF) * BN_ + o) = r;
            }
        }
    }
}

// ---------------------------------------------------------------------------
// K6: conv branches. A-halo restructure: per kc-chunk stage hT rows
//     [t0-d, t0+127+d] ONCE (plus 3 tap weight tiles), then 48 MFMA between
//     one barrier pair (3 taps x 16). Barriers/block 48 -> 16.
// ---------------------------------------------------------------------------
__global__ __launch_bounds__(256) void k_conv(
    const u16* __restrict__ hT, const u16* __restrict__ wb, u16* __restrict__ f)
{
    __shared__ u16 As[576 * 8];        // halo: 136 rows x 32 k (+dup tail)
    __shared__ u16 Bs[3 * 512 * 8];    // 3 taps x 128 rows x 32 k
    int tid = threadIdx.x;
    int t0 = blockIdx.x * 128;
    int o0 = blockIdx.y * 128;
    int nb = blockIdx.z;
    int n = nb >> 4, b = nb & 15;
    int d = n + 1;
    int lane = tid & 63, wv = tid >> 6;
    int m_off = (wv & 1) * 64, n_off = (wv >> 1) * 64;
    int lr = lane & 15, g = lane >> 4;

    // staging offsets (slot q -> row=q>>2, stored pos=q&3 holds global chunk
    // pos^((row>>1)&3)); two full passes + wave-0 tail for the halo
    int q1 = tid + 256;
    size_t off0 = (size_t)(tid >> 2) * BN_ + (((tid & 3) ^ ((tid >> 3) & 3)) * 8);
    size_t off1 = (size_t)(q1 >> 2) * BN_ + (((q1 & 3) ^ ((q1 >> 3) & 3)) * 8);
    int q2 = 512 + (lane & 31);        // halo tail rows 128..135 (upper lanes dup)
    size_t off2 = (size_t)(q2 >> 2) * BN_ + (((q2 & 3) ^ ((q2 >> 3) & 3)) * 8);
    u16* lA0 = As + (size_t)(wv * 64) * 8;
    u16* lA1 = As + (size_t)(256 + wv * 64) * 8;
    u16* lA2 = As + (size_t)512 * 8;
    u16* lB0 = Bs + (size_t)(wv * 64) * 8;          // + tap*4096
    u16* lB1 = Bs + (size_t)(256 + wv * 64) * 8;

    int sw = (g ^ ((lr >> 1) & 3)) * 8;
    int fB[4];
#pragma unroll
    for (int nn = 0; nn < 4; nn++) fB[nn] = (n_off + nn * 16 + lr) * 32 + sw;

    f32x4 zz = {0.f, 0.f, 0.f, 0.f};
    f32x4 acc[4][4];
#pragma unroll
    for (int m = 0; m < 4; m++)
#pragma unroll
        for (int nn = 0; nn < 4; nn++) acc[m][nn] = zz;

    // halo base: row ha corresponds to t = t0 + ha - d
    const u16* Agh = hT + (size_t)(b * TP_H + t0 - d + HOFF) * BN_;
    const u16* Bg[3];
#pragma unroll
    for (int tap = 0; tap < 3; tap++)
        Bg[tap] = wb + (size_t)((n * 3 + tap) * OUT_ + o0) * BN_;

    for (int kc = 0; kc < BN_; kc += 32) {
        gld16(Agh + off0 + kc, lA0);
        gld16(Agh + off1 + kc, lA1);
        if (wv == 0) gld16(Agh + off2 + kc, lA2);
#pragma unroll
        for (int tap = 0; tap < 3; tap++) {
            gld16(Bg[tap] + off0 + kc, lB0 + tap * 4096);
            gld16(Bg[tap] + off1 + kc, lB1 + tap * 4096);
        }
        __syncthreads();
#pragma unroll
        for (int tap = 0; tap < 3; tap++) {
            int rsh = d * tap;          // halo row shift for this tap
            bf16x8 af[4], bfr[4];
#pragma unroll
            for (int m = 0; m < 4; m++) {
                int row = m_off + m * 16 + lr + rsh;
                af[m] = *reinterpret_cast<const bf16x8*>(
                    As + row * 32 + ((g ^ ((row >> 1) & 3)) * 8));
            }
#pragma unroll
            for (int nn = 0; nn < 4; nn++)
                bfr[nn] = *reinterpret_cast<const bf16x8*>(Bs + tap * 4096 + fB[nn]);
#pragma unroll
            for (int m = 0; m < 4; m++)
#pragma unroll
                for (int nn = 0; nn < 4; nn++)
                    acc[m][nn] = __builtin_amdgcn_mfma_f32_16x16x32_bf16(af[m], bfr[nn], acc[m][nn], 0, 0, 0);
        }
        __syncthreads();
    }

    int qr = (lane >> 4) * 4;
#pragma unroll
    for (int m = 0; m < 4; m++) {
        int t = t0 + m_off + m * 16 + qr;     // 4 consecutive t per lane
#pragma unroll
        for (int nn = 0; nn < 4; nn++) {
            int o = o0 + n_off + nn * 16 + lr;
            f32x4 v = acc[m][nn];
            u16* dst = f + ((size_t)(n * B_ + b) * OUT_ + o) * T_ + t;
            if (t + 3 < T_) {
                u16x4 r;
                r.x = f2b(v.x); r.y = f2b(v.y); r.z = f2b(v.z); r.w = f2b(v.w);
                *reinterpret_cast<u16x4*>(dst) = r;
            } else {
                if (t + 0 < T_) dst[0] = f2b(v.x);
                if (t + 1 < T_) dst[1] = f2b(v.y);
                if (t + 2 < T_) dst[2] = f2b(v.z);
                if (t + 3 < T_) dst[3] = f2b(v.w);
            }
        }
    }
}

// ---------------------------------------------------------------------------
// K7: per-(b,o) high-order stats over t — vectorized u16x8 loads (2000=250x8)
// ---------------------------------------------------------------------------
__global__ __launch_bounds__(256) void k_stats(
    const u16* __restrict__ f, float* __restrict__ stats)
{
    int bo = blockIdx.x;
    int tid = threadIdx.x;
    const size_t stride = (size_t)B_ * OUT_ * T_;
    double s1 = 0, s2 = 0, s3 = 0, s4 = 0;
    if (tid < 250) {
        const u16* p0 = f + (size_t)bo * T_ + tid * 8;
        u16x8 a0 = *reinterpret_cast<const u16x8*>(p0);
        u16x8 a1 = *reinterpret_cast<const u16x8*>(p0 + stride);
        u16x8 a2 = *reinterpret_cast<const u16x8*>(p0 + 2 * stride);
#pragma unroll
        for (int j = 0; j < 8; j++) {
            float v = b2f(a0[j]) + b2f(a1[j]) + b2f(a2[j]);
            double dd = (double)v, d2 = dd * dd;
            s1 += dd; s2 += d2; s3 += d2 * dd; s4 += d2 * d2;
        }
    }
    for (int off = 32; off > 0; off >>= 1) {
        s1 += __shfl_down(s1, off);
        s2 += __shfl_down(s2, off);
        s3 += __shfl_down(s3, off);
        s4 += __shfl_down(s4, off);
    }
    __shared__ double red[4][4];
    int lane = tid & 63, wv = tid >> 6;
    if (lane == 0) { red[wv][0] = s1; red[wv][1] = s2; red[wv][2] = s3; red[wv][3] = s4; }
    __syncthreads();
    if (tid == 0) {
        double a1 = 0, a2 = 0, a3 = 0, a4 = 0;
        for (int w = 0; w < 4; w++) { a1 += red[w][0]; a2 += red[w][1]; a3 += red[w][2]; a4 += red[w][3]; }
        const double Tn = (double)T_;
        double m1 = a1 / Tn, m2 = a2 / Tn, m3 = a3 / Tn, m4 = a4 / Tn;
        double c2 = m2 - m1 * m1; if (c2 < 0) c2 = 0;
        double stdv = sqrt(c2 * (Tn / (Tn - 1.0)));
        double sc = stdv > 0.01 ? stdv : 0.01;
        double c3 = m3 - 3.0 * m1 * m2 + 2.0 * m1 * m1 * m1;
        double c4 = m4 - 4.0 * m1 * m3 + 6.0 * m1 * m1 * m2 - 3.0 * m1 * m1 * m1 * m1;
        int b = bo >> 9, o = bo & 511;
        float* sp = stats + (size_t)b * 2048;
        sp[o]        = (float)m1;
        sp[512 + o]  = (float)stdv;
        sp[1024 + o] = (float)(c3 / (sc * sc * sc));
        sp[1536 + o] = (float)(c4 / (sc * sc * sc * sc));
    }
}

// ---------------------------------------------------------------------------
// K8: z[b][r] = stats[b] . sel_W1[r] + sel_b1[r]  — one wave per (b,r)
// ---------------------------------------------------------------------------
__global__ __launch_bounds__(256) void k_sel1(
    const float* __restrict__ stats, const float* __restrict__ W1s,
    const float* __restrict__ b1s, float* __restrict__ z)
{
    int gid = blockIdx.x * 4 + (threadIdx.x >> 6);   // b*512 + r
    int lane = threadIdx.x & 63;
    int b = gid >> 9, r = gid & 511;
    const float4* wp = reinterpret_cast<const float4*>(W1s + (size_t)r * 2048 + lane * 32);
    const float4* sp = reinterpret_cast<const float4*>(stats + (size_t)b * 2048 + lane * 32);
    float acc = 0.f;
#pragma unroll
    for (int j = 0; j < 8; j++) {
        float4 w = wp[j], s = sp[j];
        acc += w.x * s.x + w.y * s.y + w.z * s.z + w.w * s.w;
    }
#pragma unroll
    for (int off = 32; off > 0; off >>= 1) acc += __shfl_down(acc, off);
    if (lane == 0) z[gid] = acc + b1s[r];
}

// ---------------------------------------------------------------------------
// K9: s[b][n][c] = softmax_n( z[b] . sel_W2[n][c] + sel_b2[n][c] ) — wave/(b,c)
// ---------------------------------------------------------------------------
__global__ __launch_bounds__(256) void k_sel2(
    const float* __restrict__ z, const float* __restrict__ W2s,
    const float* __restrict__ b2s, float* __restrict__ s)
{
    int gid = blockIdx.x * 4 + (threadIdx.x >> 6);   // b*512 + c
    int lane = threadIdx.x & 63;
    int b = gid >> 9, c = gid & 511;
    const float4* zp = reinterpret_cast<const float4*>(z + (size_t)b * 512 + lane * 8);
    float4 z0 = zp[0], z1 = zp[1];
    float a[3];
#pragma unroll
    for (int n = 0; n < 3; n++) {
        const float4* wp = reinterpret_cast<const float4*>(W2s + (size_t)(n * 512 + c) * 512 + lane * 8);
        float4 w0 = wp[0], w1 = wp[1];
        float acc = z0.x * w0.x + z0.y * w0.y + z0.z * w0.z + z0.w * w0.w
                  + z1.x * w1.x + z1.y * w1.y + z1.z * w1.z + z1.w * w1.w;
#pragma unroll
        for (int off = 32; off > 0; off >>= 1) acc += __shfl_down(acc, off);
        a[n] = acc + b2s[n * 512 + c];
    }
    if (lane == 0) {
        float mx = fmaxf(a[0], fmaxf(a[1], a[2]));
        float e0 = expf(a[0] - mx), e1 = expf(a[1] - mx), e2 = expf(a[2] - mx);
        float inv = 1.f / (e0 + e1 + e2);
        s[(b * 3 + 0) * 512 + c] = e0 * inv;
        s[(b * 3 + 1) * 512 + c] = e1 * inv;
        s[(b * 3 + 2) * 512 + c] = e2 * inv;
    }
}

// ---------------------------------------------------------------------------
// K10: out[b][o][t] = sum_n s[b][n][o] * f[n][b][o][t]
// ---------------------------------------------------------------------------
__global__ __launch_bounds__(256) void k_final(
    const u16* __restrict__ f, const float* __restrict__ s, float* __restrict__ out)
{
    int id = blockIdx.x * 256 + threadIdx.x;
    int row = id / 250;                         // b*512 + o
    int t = (id % 250) * 8;
    int b = row >> 9, o = row & 511;
    const size_t stride = (size_t)B_ * OUT_ * T_;
    size_t base = (size_t)row * T_ + t;
    float s0 = s[(b * 3 + 0) * 512 + o];
    float s1 = s[(b * 3 + 1) * 512 + o];
    float s2 = s[(b * 3 + 2) * 512 + o];
    u16x8 a0 = *reinterpret_cast<const u16x8*>(f + base);
    u16x8 a1 = *reinterpret_cast<const u16x8*>(f + stride + base);
    u16x8 a2 = *reinterpret_cast<const u16x8*>(f + 2 * stride + base);
    float4 r0, r1;
    r0.x = s0 * b2f(a0[0]) + s1 * b2f(a1[0]) + s2 * b2f(a2[0]);
    r0.y = s0 * b2f(a0[1]) + s1 * b2f(a1[1]) + s2 * b2f(a2[1]);
    r0.z = s0 * b2f(a0[2]) + s1 * b2f(a1[2]) + s2 * b2f(a2[2]);
    r0.w = s0 * b2f(a0[3]) + s1 * b2f(a1[3]) + s2 * b2f(a2[3]);
    r1.x = s0 * b2f(a0[4]) + s1 * b2f(a1[4]) + s2 * b2f(a2[4]);
    r1.y = s0 * b2f(a0[5]) + s1 * b2f(a1[5]) + s2 * b2f(a2[5]);
    r1.z = s0 * b2f(a0[6]) + s1 * b2f(a1[6]) + s2 * b2f(a2[6]);
    r1.w = s0 * b2f(a0[7]) + s1 * b2f(a1[7]) + s2 * b2f(a2[7]);
    *reinterpret_cast<float4*>(out + base)     = r0;
    *reinterpret_cast<float4*>(out + base + 4) = r1;
}

// ---------------------------------------------------------------------------
extern "C" void kernel_launch(void* const* d_in, const int* in_sizes, int n_in,
                              void* d_out, int out_size, void* d_ws, size_t ws_size,
                              hipStream_t stream)
{
    const float* x     = (const float*)d_in[0];
    const float* bn1g  = (const float*)d_in[1];
    const float* bn1b  = (const float*)d_in[2];
    const float* bn1m  = (const float*)d_in[3];
    const float* bn1v  = (const float*)d_in[4];
    const float* W1    = (const float*)d_in[5];
    const float* bn2g  = (const float*)d_in[6];
    const float* bn2b  = (const float*)d_in[7];
    const float* bn2m  = (const float*)d_in[8];
    const float* bn2v  = (const float*)d_in[9];
    const float* convw = (const float*)d_in[10];
    const float* selW1 = (const float*)d_in[11];
    const float* selb1 = (const float*)d_in[12];
    const float* selW2 = (const float*)d_in[13];
    const float* selb2 = (const float*)d_in[14];
    float* out = (float*)d_out;

    // fbuf aliases xbT: xbT is dead once k_gemm1 completes; k_conv (which
    // writes fbuf) runs strictly after in stream order.
    char* ws = (char*)d_ws;
    u16*   fbuf  = (u16*)(ws);                       // 3*16*512*2000*2 = 98,304,000
    u16*   xbT   = (u16*)(ws);                       // 16*2048*1024*2  = 67,108,864 (aliased)
    u16*   hT    = (u16*)(ws + 98304000);            // 16*2064*512*2   = 33,816,576
    u16*   W1b   = (u16*)(ws + 132120576);           // 512*1024*2      =  1,048,576
    float* bias2 = (float*)(ws + 133169152);         // 512*4
    u16*   wb    = (u16*)(ws + 133171200);           // 9*512*512*2     =  4,718,592
    float* stats = (float*)(ws + 137889792);         // 16*2048*4
    float* zbuf  = (float*)(ws + 138020864);         // 16*512*4
    float* sbuf  = (float*)(ws + 138053632);         // 16*3*512*4

    k_prep_x  <<<dim3(64, 32, 16), 256, 0, stream>>>(x, bn1g, bn1b, bn1m, bn1v, xbT);
    k_prep_w1 <<<512,  256, 0, stream>>>(W1, bn2g, bn2b, bn2m, bn2v, W1b, bias2);
    k_prep_wc <<<3072, 256, 0, stream>>>(convw, wb);
    k_zero_hpad<<<2048, 256, 0, stream>>>(hT);
    k_gemm1   <<<dim3(16, 4, 16), 256, 0, stream>>>(W1b, xbT, bias2, hT);
    k_conv    <<<dim3(16, 4, 48), 256, 0, stream>>>(hT, wb, fbuf);
    k_stats   <<<8192, 256, 0, stream>>>(fbuf, stats);
    k_sel1    <<<2048, 256, 0, stream>>>(stats, selW1, selb1, zbuf);
    k_sel2    <<<2048, 256, 0, stream>>>(zbuf, selW2, selb2, sbuf);
    k_final   <<<8000, 256, 0, stream>>>(fbuf, sbuf, out);
}